// Round 8
// baseline (501.785 us; speedup 1.0000x reference)
//
#include <hip/hip_runtime.h>

constexpr int B = 8, N = 8192, S = 2048, D = 64, K = 16, C = 3 + D;

// Map float -> monotonically sortable unsigned (total order matches float <)
__device__ __forceinline__ unsigned sortable(float f) {
    unsigned u = __float_as_uint(f);
    unsigned mask = (unsigned)(((int)u) >> 31) | 0x80000000u;
    return u ^ mask;
}

// Precompute ||p||^2 per (b, n): DESCENDING no-FMA: (z*z + y*y) + x*x
// (numpy einsum('bij,bij->bi') on contiguous array: outstride0 remainder
//  switch descending fallthrough, SSE mul+add — the sklearn row_norms idiom).
__global__ void pn_kernel(const float* __restrict__ pts, float* __restrict__ pn) {
    int t = blockIdx.x * blockDim.x + threadIdx.x;  // t = b*N + n
    if (t >= B * N) return;
    int b = t >> 13, n = t & (N - 1);
    const float* P = pts + (size_t)b * 3 * N;
    float x = P[n], y = P[N + n], z = P[2 * N + n];
    pn[t] = __fadd_rn(__fadd_rn(__fmul_rn(z, z), __fmul_rn(y, y)), __fmul_rn(x, x));
}

// One wave (64 lanes) per query (b, s). Each lane scans 128 strided points,
// keeps a sorted ascending top-16 of u64 keys in registers, then the wave
// merges via 16 rounds of u64 min-butterfly.
// Distance scheme "Variant I" (sklearn euclidean_distances structure):
//   pn,qn = (z*z + y*y) + x*x              [DESC no-FMA, einsum row_norms]
//   dot   = fma(pz,qz, fma(py,qy, px*qx))  [ascending-k FMA chain (BLAS sgemm)]
//   d     = (pn - 2*dot) + qn              [(-2d + pn) + qn, same bits]
__global__ void __launch_bounds__(256) knn_kernel(const float* __restrict__ pts,
                                                  const float* __restrict__ newp,
                                                  const float* __restrict__ pn,
                                                  int* __restrict__ ind) {
    int wid = (blockIdx.x * blockDim.x + threadIdx.x) >> 6;  // global wave id = b*S + s
    int lane = threadIdx.x & 63;
    int b = wid >> 11;          // S = 2048
    int s = wid & (S - 1);
    const float* P = pts + (size_t)b * 3 * N;
    const float* PN = pn + (size_t)b * N;
    const float* Q = newp + (size_t)b * 3 * S;
    float qx = Q[s], qy = Q[S + s], qz = Q[2 * S + s];
    // ||q||^2: descending no-FMA, same scheme as pn
    float qn = __fadd_rn(__fadd_rn(__fmul_rn(qz, qz), __fmul_rn(qy, qy)), __fmul_rn(qx, qx));

    unsigned long long a[K];
#pragma unroll
    for (int i = 0; i < K; ++i) a[i] = ~0ull;

    for (int n = lane; n < N; n += 64) {
        float px = P[n], py = P[N + n], pz = P[2 * N + n];
        // ascending FMA chain: acc = px*qx; acc = fma(py,qy,acc); acc = fma(pz,qz,acc)
        float dot = __fmaf_rn(pz, qz, __fmaf_rn(py, qy, __fmul_rn(px, qx)));
        float d = __fadd_rn(__fsub_rn(PN[n], __fmul_rn(2.0f, dot)), qn);
        unsigned long long key = ((unsigned long long)sortable(d) << 32) | (unsigned)n;
        if (key < a[K - 1]) {
            // branchless sorted insert (ascending)
#pragma unroll
            for (int i = K - 1; i >= 1; --i) {
                unsigned long long lo = a[i - 1];
                a[i] = key < lo ? lo : (key < a[i] ? key : a[i]);
            }
            a[0] = key < a[0] ? key : a[0];
        }
    }

    // Wave merge: 16 rounds of u64 min all-reduce; winner lane shifts its list.
    int* my_ind = ind + (size_t)wid * K;
    for (int r = 0; r < K; ++r) {
        unsigned long long best = a[0];
#pragma unroll
        for (int m = 1; m < 64; m <<= 1) {
            unsigned long long o = __shfl_xor(best, m, 64);
            best = o < best ? o : best;
        }
        if (lane == 0) my_ind[r] = (int)(unsigned)(best & 0xffffffffu);
        bool won = (a[0] == best);
#pragma unroll
        for (int i = 0; i < K - 1; ++i) a[i] = won ? a[i + 1] : a[i];
        a[K - 1] = won ? ~0ull : a[K - 1];
    }
}

// Output: [B, C=67, K, S]; threads map so consecutive lanes write consecutive s.
__global__ void __launch_bounds__(256) gather_kernel(const float* __restrict__ pts,
                                                     const float* __restrict__ newp,
                                                     const float* __restrict__ feat,
                                                     const int* __restrict__ ind,
                                                     float* __restrict__ out) {
    int t = blockIdx.x * blockDim.x + threadIdx.x;
    int s = t & (S - 1);
    int rest = t >> 11;
    int k = rest & (K - 1);
    rest >>= 4;
    int c = rest % C;
    int b = rest / C;
    if (b >= B) return;
    int id = ind[(((size_t)b * S + s) * K) + k];
    float v;
    if (c < 3)
        v = __fsub_rn(pts[((size_t)b * 3 + c) * N + id], newp[((size_t)b * 3 + c) * S + s]);
    else
        v = feat[((size_t)b * D + (c - 3)) * N + id];
    out[t] = v;
}

extern "C" void kernel_launch(void* const* d_in, const int* in_sizes, int n_in,
                              void* d_out, int out_size, void* d_ws, size_t ws_size,
                              hipStream_t stream) {
    const float* pts = (const float*)d_in[0];   // [B, 3, N]
    const float* newp = (const float*)d_in[1];  // [B, 3, S]
    const float* feat = (const float*)d_in[2];  // [B, D, N]
    float* out = (float*)d_out;                 // [B, C, K, S]

    int* ind = (int*)d_ws;                                                // B*S*K ints (2 MB)
    float* pn = (float*)((char*)d_ws + (size_t)B * S * K * sizeof(int));  // B*N floats (256 KB)

    pn_kernel<<<(B * N + 255) / 256, 256, 0, stream>>>(pts, pn);
    knn_kernel<<<(B * S) / 4, 256, 0, stream>>>(pts, newp, pn, ind);
    gather_kernel<<<(B * C * K * S) / 256, 256, 0, stream>>>(pts, newp, feat, ind, out);
}

// Round 9
// 217.204 us; speedup vs baseline: 2.3102x; 2.3102x over previous
//
#include <hip/hip_runtime.h>

constexpr int B = 8, N = 8192, S = 2048, D = 64, K = 16, C = 3 + D;

// Map float -> monotonically sortable unsigned (total order matches float <)
__device__ __forceinline__ unsigned sortable(float f) {
    unsigned u = __float_as_uint(f);
    unsigned mask = (unsigned)(((int)u) >> 31) | 0x80000000u;
    return u ^ mask;
}

// Precompute ||p||^2 per (b, n): DESCENDING no-FMA: (z*z + y*y) + x*x  [verified R8]
__global__ void pn_kernel(const float* __restrict__ pts, float* __restrict__ pn) {
    int t = blockIdx.x * blockDim.x + threadIdx.x;  // t = b*N + n
    if (t >= B * N) return;
    int b = t >> 13, n = t & (N - 1);
    const float* P = pts + (size_t)b * 3 * N;
    float x = P[n], y = P[N + n], z = P[2 * N + n];
    pn[t] = __fadd_rn(__fadd_rn(__fmul_rn(z, z), __fmul_rn(y, y)), __fmul_rn(x, x));
}

// Verified distance scheme (R8): dot = asc FMA chain; d = (pn - 2*dot) + qn
__device__ __forceinline__ unsigned long long make_key(float px, float py, float pz, float pnv,
                                                       float qx, float qy, float qz, float qn,
                                                       int n) {
    float dot = __fmaf_rn(pz, qz, __fmaf_rn(py, qy, __fmul_rn(px, qx)));
    float d = __fadd_rn(__fsub_rn(pnv, __fmul_rn(2.0f, dot)), qn);
    return ((unsigned long long)sortable(d) << 32) | (unsigned)n;
}

// Full bitonic sort of 64 u64 keys (one per lane), ascending by lane.
__device__ __forceinline__ unsigned long long bitonic_sort64(unsigned long long v, int lane) {
#pragma unroll
    for (int k = 2; k <= 64; k <<= 1) {
#pragma unroll
        for (int j = k >> 1; j > 0; j >>= 1) {
            unsigned long long o = __shfl_xor(v, j, 64);
            bool keepmin = ((lane & k) == 0) == ((lane & j) == 0);
            v = ((v < o) == keepmin) ? v : o;
        }
    }
    return v;
}

// One wave per query. Pass 1: per-lane min -> tau = 16th-smallest lane-min
// (provable upper bound on the global 16th-smallest key). Pass 2: collect all
// keys <= tau (ballot-compact into LDS), bitonic-sort, emit first 16.
__global__ void __launch_bounds__(256) knn_kernel(const float* __restrict__ pts,
                                                  const float* __restrict__ newp,
                                                  const float* __restrict__ pn,
                                                  int* __restrict__ ind) {
    __shared__ unsigned long long buf[4 * 64];
    int wid = (blockIdx.x * blockDim.x + threadIdx.x) >> 6;  // b*S + s
    int lane = threadIdx.x & 63;
    int woff = (threadIdx.x >> 6) << 6;
    int b = wid >> 11;          // S = 2048
    int s = wid & (S - 1);
    const float* Px = pts + (size_t)b * 3 * N;
    const float* Py = Px + N;
    const float* Pz = Px + 2 * N;
    const float* PNb = pn + (size_t)b * N;
    const float* Q = newp + (size_t)b * 3 * S;
    float qx = Q[s], qy = Q[S + s], qz = Q[2 * S + s];
    float qn = __fadd_rn(__fadd_rn(__fmul_rn(qz, qz), __fmul_rn(qy, qy)), __fmul_rn(qx, qx));

    // ---- pass 1: per-lane min over 128 candidates, float4 loads ----
    unsigned long long m = ~0ull;
    for (int blk = 0; blk < N / 256; ++blk) {
        int n0 = blk * 256 + lane * 4;
        float4 vx = *(const float4*)(Px + n0);
        float4 vy = *(const float4*)(Py + n0);
        float4 vz = *(const float4*)(Pz + n0);
        float4 vn = *(const float4*)(PNb + n0);
        float ax[4] = {vx.x, vx.y, vx.z, vx.w};
        float ay[4] = {vy.x, vy.y, vy.z, vy.w};
        float az[4] = {vz.x, vz.y, vz.z, vz.w};
        float an[4] = {vn.x, vn.y, vn.z, vn.w};
#pragma unroll
        for (int i = 0; i < 4; ++i) {
            unsigned long long key = make_key(ax[i], ay[i], az[i], an[i], qx, qy, qz, qn, n0 + i);
            m = key < m ? key : m;
        }
    }
    unsigned long long tau = __shfl(bitonic_sort64(m, lane), 15, 64);

    // ---- pass 2: collect all keys <= tau ----
    int cnt = 0;
    for (int blk = 0; blk < N / 256; ++blk) {
        int n0 = blk * 256 + lane * 4;
        float4 vx = *(const float4*)(Px + n0);
        float4 vy = *(const float4*)(Py + n0);
        float4 vz = *(const float4*)(Pz + n0);
        float4 vn = *(const float4*)(PNb + n0);
        float ax[4] = {vx.x, vx.y, vx.z, vx.w};
        float ay[4] = {vy.x, vy.y, vy.z, vy.w};
        float az[4] = {vz.x, vz.y, vz.z, vz.w};
        float an[4] = {vn.x, vn.y, vn.z, vn.w};
#pragma unroll
        for (int i = 0; i < 4; ++i) {
            unsigned long long key = make_key(ax[i], ay[i], az[i], an[i], qx, qy, qz, qn, n0 + i);
            bool pred = key <= tau;
            unsigned long long mask = __ballot(pred);
            if (mask) {
                int pos = cnt + (int)__popcll(mask & ((1ull << lane) - 1ull));
                if (pred && pos < 64) buf[woff + pos] = key;
                cnt += (int)__popcll(mask);
            }
        }
    }
    __syncthreads();  // uniform; also orders LDS writes before reads

    int* my_ind = ind + (size_t)wid * K;
    if (cnt <= 64) {
        unsigned long long key = (lane < cnt) ? buf[woff + lane] : ~0ull;
        key = bitonic_sort64(key, lane);
        if (lane < K) my_ind[lane] = (int)(unsigned)key;  // low 32 bits = index
    } else {
        // Exact fallback (never taken on random data): per-lane sorted top-16 + wave merge.
        unsigned long long a[K];
#pragma unroll
        for (int i = 0; i < K; ++i) a[i] = ~0ull;
        for (int n = lane; n < N; n += 64) {
            unsigned long long key = make_key(Px[n], Py[n], Pz[n], PNb[n], qx, qy, qz, qn, n);
            if (key < a[K - 1]) {
#pragma unroll
                for (int i = K - 1; i >= 1; --i) {
                    unsigned long long lo = a[i - 1];
                    a[i] = key < lo ? lo : (key < a[i] ? key : a[i]);
                }
                a[0] = key < a[0] ? key : a[0];
            }
        }
        for (int r = 0; r < K; ++r) {
            unsigned long long best = a[0];
#pragma unroll
            for (int mm = 1; mm < 64; mm <<= 1) {
                unsigned long long o = __shfl_xor(best, mm, 64);
                best = o < best ? o : best;
            }
            if (lane == 0) my_ind[r] = (int)(unsigned)best;
            bool won = (a[0] == best);
#pragma unroll
            for (int i = 0; i < K - 1; ++i) a[i] = won ? a[i + 1] : a[i];
            a[K - 1] = won ? ~0ull : a[K - 1];
        }
    }
}

// Output: [B, C=67, K, S]; threads map so consecutive lanes write consecutive s.
__global__ void __launch_bounds__(256) gather_kernel(const float* __restrict__ pts,
                                                     const float* __restrict__ newp,
                                                     const float* __restrict__ feat,
                                                     const int* __restrict__ ind,
                                                     float* __restrict__ out) {
    int t = blockIdx.x * blockDim.x + threadIdx.x;
    int s = t & (S - 1);
    int rest = t >> 11;
    int k = rest & (K - 1);
    rest >>= 4;
    int c = rest % C;
    int b = rest / C;
    if (b >= B) return;
    int id = ind[(((size_t)b * S + s) * K) + k];
    float v;
    if (c < 3)
        v = __fsub_rn(pts[((size_t)b * 3 + c) * N + id], newp[((size_t)b * 3 + c) * S + s]);
    else
        v = feat[((size_t)b * D + (c - 3)) * N + id];
    out[t] = v;
}

extern "C" void kernel_launch(void* const* d_in, const int* in_sizes, int n_in,
                              void* d_out, int out_size, void* d_ws, size_t ws_size,
                              hipStream_t stream) {
    const float* pts = (const float*)d_in[0];   // [B, 3, N]
    const float* newp = (const float*)d_in[1];  // [B, 3, S]
    const float* feat = (const float*)d_in[2];  // [B, D, N]
    float* out = (float*)d_out;                 // [B, C, K, S]

    int* ind = (int*)d_ws;                                                // B*S*K ints (2 MB)
    float* pn = (float*)((char*)d_ws + (size_t)B * S * K * sizeof(int));  // B*N floats (256 KB)

    pn_kernel<<<(B * N + 255) / 256, 256, 0, stream>>>(pts, pn);
    knn_kernel<<<(B * S) / 4, 256, 0, stream>>>(pts, newp, pn, ind);
    gather_kernel<<<(B * C * K * S) / 256, 256, 0, stream>>>(pts, newp, feat, ind, out);
}

// Round 10
// 114.765 us; speedup vs baseline: 4.3723x; 1.8926x over previous
//
#include <hip/hip_runtime.h>

constexpr int B = 8, N = 8192, S = 2048, D = 64, K = 16, C = 3 + D;
constexpr int G = 4;  // queries per wave

// Map float -> monotonically sortable unsigned (total order matches float <)
__device__ __forceinline__ unsigned sortable(float f) {
    unsigned u = __float_as_uint(f);
    unsigned mask = (unsigned)(((int)u) >> 31) | 0x80000000u;
    return u ^ mask;
}

// Wave-uniform load -> SGPR
__device__ __forceinline__ float uload(const float* p) {
    return __uint_as_float(__builtin_amdgcn_readfirstlane(__float_as_uint(*p)));
}

// Verified scheme (R8): pn desc-noFMA; dot asc-FMA; d = (pn - 2*dot) + qn
__device__ __forceinline__ float make_d(float px, float py, float pz, float pnv,
                                        float qx, float qy, float qz, float qn) {
    float dot = __fmaf_rn(pz, qz, __fmaf_rn(py, qy, __fmul_rn(px, qx)));
    return __fadd_rn(__fsub_rn(pnv, __fmul_rn(2.0f, dot)), qn);
}

__device__ __forceinline__ float bitonic_sort64_f32(float v, int lane) {
#pragma unroll
    for (int k = 2; k <= 64; k <<= 1)
#pragma unroll
        for (int j = k >> 1; j > 0; j >>= 1) {
            float o = __shfl_xor(v, j, 64);
            bool keepmin = ((lane & k) == 0) == ((lane & j) == 0);
            float mn = fminf(v, o), mx = fmaxf(v, o);
            v = keepmin ? mn : mx;
        }
    return v;
}

__device__ __forceinline__ unsigned long long bitonic_sort64_u64(unsigned long long v, int lane) {
#pragma unroll
    for (int k = 2; k <= 64; k <<= 1)
#pragma unroll
        for (int j = k >> 1; j > 0; j >>= 1) {
            unsigned long long o = __shfl_xor(v, j, 64);
            bool keepmin = ((lane & k) == 0) == ((lane & j) == 0);
            v = ((v < o) == keepmin) ? v : o;
        }
    return v;
}

// pts4[b][n] = {x, y, z, ||p||^2}; norm = (z*z + y*y) + x*x desc no-FMA [verified R8]
__global__ void pack_kernel(const float* __restrict__ pts, float4* __restrict__ pts4) {
    int t = blockIdx.x * blockDim.x + threadIdx.x;
    if (t >= B * N) return;
    int b = t >> 13, n = t & (N - 1);
    const float* P = pts + (size_t)b * 3 * N;
    float x = P[n], y = P[N + n], z = P[2 * N + n];
    float pn = __fadd_rn(__fadd_rn(__fmul_rn(z, z), __fmul_rn(y, y)), __fmul_rn(x, x));
    pts4[t] = make_float4(x, y, z, pn);
}

// feat [B][D][N] -> featT [B][N][D], LDS-tiled 64x64
__global__ void __launch_bounds__(256) transpose_kernel(const float* __restrict__ feat,
                                                        float* __restrict__ featT) {
    __shared__ float tile[64][65];
    int b = blockIdx.x >> 7;  // N/64 = 128 tiles per batch
    int n0 = (blockIdx.x & 127) << 6;
    int col = threadIdx.x & 63;
    int crow = threadIdx.x >> 6;  // 0..3
    const float* F = feat + (size_t)b * D * N;
#pragma unroll
    for (int i = 0; i < 16; ++i) {
        int c = i * 4 + crow;
        tile[c][col] = F[(size_t)c * N + n0 + col];
    }
    __syncthreads();
    float* FT = featT + ((size_t)b * N + n0) * D;
#pragma unroll
    for (int i = 0; i < 16; ++i) {
        int nl = i * 4 + crow;
        FT[(size_t)nl * D + col] = tile[col][nl];
    }
}

// One wave per G=4 queries. Pass 1: per-lane f32 min per query -> tau = 16th
// lane-min (valid upper bound on global 16th distance). Pass 2: collect all
// d <= tau as u64 (d,idx) keys, bitonic sort, emit 16. Exact fallback if >64.
__global__ void __launch_bounds__(256) knn_kernel(const float4* __restrict__ pts4,
                                                  const float* __restrict__ newp,
                                                  int* __restrict__ ind) {
    __shared__ unsigned long long buf[4][G][64];
    int wib = threadIdx.x >> 6;
    int lane = threadIdx.x & 63;
    int wid = blockIdx.x * 4 + wib;
    int b = wid >> 9;              // S/G = 512 waves per batch
    int sbase = (wid & 511) * G;
    const float4* P4 = pts4 + (size_t)b * N;
    const float* Q = newp + (size_t)b * 3 * S;
    float qx[G], qy[G], qz[G], qn[G];
#pragma unroll
    for (int g = 0; g < G; ++g) {
        int s = sbase + g;
        qx[g] = uload(Q + s);
        qy[g] = uload(Q + S + s);
        qz[g] = uload(Q + 2 * S + s);
        qn[g] = __fadd_rn(__fadd_rn(__fmul_rn(qz[g], qz[g]), __fmul_rn(qy[g], qy[g])),
                          __fmul_rn(qx[g], qx[g]));
    }

    // ---- pass 1 ----
    float m[G];
#pragma unroll
    for (int g = 0; g < G; ++g) m[g] = __int_as_float(0x7f800000);  // +inf
    for (int blk = 0; blk < N / 256; ++blk) {
        int nb = blk * 256 + lane;
        float4 cc[4] = {P4[nb], P4[nb + 64], P4[nb + 128], P4[nb + 192]};
#pragma unroll
        for (int i = 0; i < 4; ++i) {
#pragma unroll
            for (int g = 0; g < G; ++g) {
                float d = make_d(cc[i].x, cc[i].y, cc[i].z, cc[i].w, qx[g], qy[g], qz[g], qn[g]);
                m[g] = fminf(m[g], d);
            }
        }
    }
    float tau[G];
#pragma unroll
    for (int g = 0; g < G; ++g) tau[g] = __shfl(bitonic_sort64_f32(m[g], lane), 15, 64);

    // ---- pass 2 ----
    int cnt[G] = {0, 0, 0, 0};
    for (int blk = 0; blk < N / 256; ++blk) {
        int nb = blk * 256 + lane;
        float4 cc[4] = {P4[nb], P4[nb + 64], P4[nb + 128], P4[nb + 192]};
#pragma unroll
        for (int i = 0; i < 4; ++i) {
            int n = nb + i * 64;
#pragma unroll
            for (int g = 0; g < G; ++g) {
                float d = make_d(cc[i].x, cc[i].y, cc[i].z, cc[i].w, qx[g], qy[g], qz[g], qn[g]);
                bool pred = d <= tau[g];
                unsigned long long mask = __ballot(pred);
                if (mask) {
                    int pos = cnt[g] + (int)__popcll(mask & ((1ull << lane) - 1ull));
                    if (pred && pos < 64)
                        buf[wib][g][pos] = ((unsigned long long)sortable(d) << 32) | (unsigned)n;
                    cnt[g] += (int)__popcll(mask);
                }
            }
        }
    }
    __syncthreads();

#pragma unroll
    for (int g = 0; g < G; ++g) {
        int* my_ind = ind + ((size_t)b * S + sbase + g) * K;
        if (cnt[g] <= 64) {
            unsigned long long key = (lane < cnt[g]) ? buf[wib][g][lane] : ~0ull;
            key = bitonic_sort64_u64(key, lane);
            if (lane < K) my_ind[lane] = (int)(unsigned)key;
        } else {
            // Exact fallback (not expected on random data)
            unsigned long long a[K];
#pragma unroll
            for (int i = 0; i < K; ++i) a[i] = ~0ull;
            for (int n = lane; n < N; n += 64) {
                float4 c = P4[n];
                float d = make_d(c.x, c.y, c.z, c.w, qx[g], qy[g], qz[g], qn[g]);
                unsigned long long key = ((unsigned long long)sortable(d) << 32) | (unsigned)n;
                if (key < a[K - 1]) {
#pragma unroll
                    for (int i = K - 1; i >= 1; --i) {
                        unsigned long long lo = a[i - 1];
                        a[i] = key < lo ? lo : (key < a[i] ? key : a[i]);
                    }
                    a[0] = key < a[0] ? key : a[0];
                }
            }
            for (int r = 0; r < K; ++r) {
                unsigned long long best = a[0];
#pragma unroll
                for (int mm = 1; mm < 64; mm <<= 1) {
                    unsigned long long o = __shfl_xor(best, mm, 64);
                    best = o < best ? o : best;
                }
                if (lane == 0) my_ind[r] = (int)(unsigned)best;
                bool won = (a[0] == best);
#pragma unroll
                for (int i = 0; i < K - 1; ++i) a[i] = won ? a[i + 1] : a[i];
                a[K - 1] = won ? ~0ull : a[K - 1];
            }
        }
    }
}

// Output [B][C][K][S]. t -> (b, g, k, s); g=0: 3 coord channels from pts4;
// g=1..16: 4 feat channels via one float4 from featT (or 4 scalar loads).
__global__ void __launch_bounds__(256) gather_kernel(const float4* __restrict__ pts4,
                                                     const float* __restrict__ newp,
                                                     const float* __restrict__ feat,
                                                     const float* __restrict__ featT,
                                                     const int* __restrict__ ind,
                                                     float* __restrict__ out, int useT) {
    int t = blockIdx.x * blockDim.x + threadIdx.x;
    int s = t & (S - 1);
    int k = (t >> 11) & (K - 1);
    int rest = t >> 15;
    int g = rest % 17;
    int b = rest / 17;
    if (b >= B) return;
    int id = ind[((size_t)b * S + s) * K + k];
    size_t KS = (size_t)K * S;
    if (g == 0) {
        float4 p = pts4[(size_t)b * N + id];
        const float* Q = newp + (size_t)b * 3 * S;
        float* o = out + ((size_t)b * C * K + k) * S + s;
        o[0] = __fsub_rn(p.x, Q[s]);
        o[KS] = __fsub_rn(p.y, Q[S + s]);
        o[2 * KS] = __fsub_rn(p.z, Q[2 * S + s]);
    } else {
        int cb = (g - 1) * 4;
        float4 f;
        if (useT) {
            f = *(const float4*)(featT + ((size_t)b * N + id) * D + cb);
        } else {
            const float* F = feat + (size_t)b * D * N;
            f = make_float4(F[(size_t)cb * N + id], F[(size_t)(cb + 1) * N + id],
                            F[(size_t)(cb + 2) * N + id], F[(size_t)(cb + 3) * N + id]);
        }
        float* o = out + (((size_t)b * C + 3 + cb) * K + k) * S + s;
        o[0] = f.x;
        o[KS] = f.y;
        o[2 * KS] = f.z;
        o[3 * KS] = f.w;
    }
}

extern "C" void kernel_launch(void* const* d_in, const int* in_sizes, int n_in,
                              void* d_out, int out_size, void* d_ws, size_t ws_size,
                              hipStream_t stream) {
    const float* pts = (const float*)d_in[0];   // [B, 3, N]
    const float* newp = (const float*)d_in[1];  // [B, 3, S]
    const float* feat = (const float*)d_in[2];  // [B, D, N]
    float* out = (float*)d_out;                 // [B, C, K, S]

    size_t off_ind = 0;
    size_t off_pts4 = (size_t)B * S * K * sizeof(int);              // 2 MB
    size_t off_featT = off_pts4 + (size_t)B * N * sizeof(float4);   // +1 MB
    size_t need = off_featT + (size_t)B * N * D * sizeof(float);    // +16 MB
    int* ind = (int*)((char*)d_ws + off_ind);
    float4* pts4 = (float4*)((char*)d_ws + off_pts4);
    float* featT = (float*)((char*)d_ws + off_featT);
    int useT = (ws_size >= need) ? 1 : 0;

    pack_kernel<<<(B * N) / 256, 256, 0, stream>>>(pts, pts4);
    if (useT) transpose_kernel<<<B * (N / 64), 256, 0, stream>>>(feat, featT);
    knn_kernel<<<(B * S) / (G * 4), 256, 0, stream>>>(pts4, newp, ind);
    gather_kernel<<<(B * 17 * K * S) / 256, 256, 0, stream>>>(pts4, newp, feat, featT, ind, out, useT);
}